// Round 8
// baseline (228.508 us; speedup 1.0000x reference)
//
#include <hip/hip_runtime.h>

// DeepWalk hierarchical-softmax loss:
//   out = -sum_{e,t} mask[v,t] * log_sigmoid(signs[v,t] * dot(Z1[u], Z2[paths[v,t]]))
//
// Identities: log_sigmoid(y) = min(y,0) - log(1+exp(-|y|));
//   sum log(1+e) -> log(prod (1+e)); padded levels (s==0) contribute exactly 0.
//
// R8: 32-lane subgroup per edge (4 halfs of the row per lane), fp16 Z2 repack
// (proven R4) + fdot2 dot (2 instr/level). Quad reduce-scatter over 4 levels:
// lane ends owning level t+(lane&3) (8x replication -> final scale 1/8);
// per-lane sign loaded directly (no selects). launch_bounds(256,4) gives the
// unrolled loop a 128-VGPR budget for ~16 gathers in flight.

typedef _Float16 half8  __attribute__((ext_vector_type(8)));
typedef _Float16 half4v __attribute__((ext_vector_type(4)));
typedef _Float16 half2v __attribute__((ext_vector_type(2)));
typedef float    floatx2 __attribute__((ext_vector_type(2)));

#if defined(__has_builtin)
#if __has_builtin(__builtin_amdgcn_fdot2)
#define HAVE_FDOT2 1
#endif
#endif

__global__ __launch_bounds__(256) void dw_pack_f16(
    const float* __restrict__ src, _Float16* __restrict__ dst, int n8)
{
    const int i = blockIdx.x * 256 + threadIdx.x;
    if (i < n8) {
        const float4* s = (const float4*)src;
        const float4 a = s[2 * i];
        const float4 b = s[2 * i + 1];
        half8 h;
        h[0] = (_Float16)a.x; h[1] = (_Float16)a.y;
        h[2] = (_Float16)a.z; h[3] = (_Float16)a.w;
        h[4] = (_Float16)b.x; h[5] = (_Float16)b.y;
        h[6] = (_Float16)b.z; h[7] = (_Float16)b.w;
        ((half8*)dst)[i] = h;
    }
}

__device__ __forceinline__ float dw_dot4h(
    const _Float16* __restrict__ Z2h, int p, int lane5,
    half2v zh01, half2v zh23)
{
    union { half4v h4; half2v h2[2]; } w;
    w.h4 = ((const half4v*)(Z2h + (size_t)(unsigned)p * 128))[lane5];  // 8B
#ifdef HAVE_FDOT2
    float d = __builtin_amdgcn_fdot2(w.h2[0], zh01, 0.0f, false);
    d = __builtin_amdgcn_fdot2(w.h2[1], zh23, d, false);
    return d;
#else
    float d = (float)w.h4[0] * (float)zh01[0];
    d = fmaf((float)w.h4[1], (float)zh01[1], d);
    d = fmaf((float)w.h4[2], (float)zh23[0], d);
    d = fmaf((float)w.h4[3], (float)zh23[1], d);
    return d;
#endif
}

template <int LT>
__global__ __launch_bounds__(256, 4) void dw_kernel32(
    const int* __restrict__ edges,
    const float* __restrict__ Z1,
    const _Float16* __restrict__ Z2h,
    const int* __restrict__ paths,
    const float* __restrict__ signs,
    float* __restrict__ partials,
    int E, int L_rt)
{
    const int tid   = blockIdx.x * blockDim.x + threadIdx.x;
    const int group = tid >> 5;        // one edge per 32-lane subgroup
    const int lane5 = tid & 31;
    const int L     = (LT > 0) ? LT : L_rt;

    float acc = 0.0f;

    if (group < E) {
        const int u = edges[2 * group];
        const int v = edges[2 * group + 1];

        // z = Z1[u] floats [4*lane5 .. 4*lane5+3] (coalesced 512B row)
        const float4 z4 = ((const float4*)(Z1 + (size_t)u * 128))[lane5];
        half2v zh01, zh23;
        zh01[0] = (_Float16)z4.x; zh01[1] = (_Float16)z4.y;
        zh23[0] = (_Float16)z4.z; zh23[1] = (_Float16)z4.w;

        const int*   pr = paths + (size_t)v * L;
        const float* sr = signs + (size_t)v * L;

        const bool b0 = lane5 & 1;
        const bool b1 = lane5 & 2;
        const int  own = lane5 & 3;    // this lane owns level t + own

        float accm = 0.0f;   // sum of min(y,0)           (8x replicated)
        float prod = 1.0f;   // prod of (1 + exp(-|y|))   (8x replicated)

        int t = 0;
#pragma unroll
        for (; t + 4 <= L; t += 4) {
            const int p0 = pr[t + 0], p1 = pr[t + 1];
            const int p2 = pr[t + 2], p3 = pr[t + 3];
            const float s = sr[t + own];            // own level's sign

            const float d0 = dw_dot4h(Z2h, p0, lane5, zh01, zh23);
            const float d1 = dw_dot4h(Z2h, p1, lane5, zh01, zh23);
            const float d2 = dw_dot4h(Z2h, p2, lane5, zh01, zh23);
            const float d3 = dw_dot4h(Z2h, p3, lane5, zh01, zh23);

            // quad reduce-scatter over 32 lanes: lane ends with full dot of
            // level t+own.  stage1 pairs levels (0,1) and (2,3), stage2 pairs
            // the results, stages 3-5 finish the 32-lane tree.
            const float ua = b0 ? d0 : d1, ka = b0 ? d1 : d0;
            const float av = ka + __shfl_xor(ua, 1);
            const float ub = b0 ? d2 : d3, kb = b0 ? d3 : d2;
            const float bv = kb + __shfl_xor(ub, 1);
            const float uc = b1 ? av : bv, kc = b1 ? bv : av;
            float cv = kc + __shfl_xor(uc, 2);
            cv += __shfl_xor(cv, 4);
            cv += __shfl_xor(cv, 8);
            cv += __shfl_xor(cv, 16);

            const float y  = s * cv;
            const float ex = __expf(-fabsf(y));          // 1.0 when padded
            prod = prod * fmaf(fabsf(s), ex, 1.0f);      // *1 when padded
            accm += fminf(y, 0.0f);                      // +0 when padded
        }
        // tail levels (L%4): full 32-lane butterfly, counted on lanes 0..7
#pragma unroll
        for (; t < L; ++t) {
            const int   p = pr[t];
            const float s = sr[t];
            float d = dw_dot4h(Z2h, p, lane5, zh01, zh23);
            d += __shfl_xor(d, 1);
            d += __shfl_xor(d, 2);
            d += __shfl_xor(d, 4);
            d += __shfl_xor(d, 8);
            d += __shfl_xor(d, 16);
            const float y  = s * d;
            const float ex = __expf(-fabsf(y));
            const float m  = (lane5 < 8) ? 1.0f : 0.0f;
            prod = prod * fmaf(m * fabsf(s), ex, 1.0f);
            accm += m * fminf(y, 0.0f);
        }

        acc = accm - __logf(prod);   // per-edge contribution (8x replicated)
    }

    for (int off = 32; off >= 1; off >>= 1)
        acc += __shfl_down(acc, off);

    __shared__ float ws[4];
    const int wid = threadIdx.x >> 6;
    if ((threadIdx.x & 63) == 0) ws[wid] = acc;
    __syncthreads();
    if (threadIdx.x == 0)
        partials[blockIdx.x] = ws[0] + ws[1] + ws[2] + ws[3];
}

// fp32 fallback if ws too small (16x replication -> *0.5 here, *1/8 in reduce)
template <int LT>
__global__ __launch_bounds__(256) void dw_kernel_t(
    const int* __restrict__ edges,
    const float* __restrict__ Z1,
    const float* __restrict__ Z2,
    const int* __restrict__ paths,
    const float* __restrict__ signs,
    float* __restrict__ partials,
    int E, int L_rt)
{
    const int tid   = blockIdx.x * blockDim.x + threadIdx.x;
    const int group = tid >> 4;
    const int lane  = tid & 15;
    const int L     = (LT > 0) ? LT : L_rt;

    float acc = 0.0f;

    if (group < E) {
        const int u = edges[2 * group];
        const int v = edges[2 * group + 1];

        const float4* zr = (const float4*)(Z1 + (size_t)u * 128);
        const float4 za = zr[lane];
        const float4 zb = zr[lane + 16];

        const int*    pr  = paths + (size_t)v * L;
        const float*  sr  = signs + (size_t)v * L;
        const float4* Z2v = (const float4*)Z2;

        float accm = 0.0f;
        float prod = 1.0f;

#pragma unroll
        for (int t = 0; t < L; ++t) {
            const int   p = pr[t];
            const float s = sr[t];

            const float4 wa = Z2v[p * 32 + lane];
            const float4 wb = Z2v[p * 32 + lane + 16];

            float d = za.x * wa.x + za.y * wa.y + za.z * wa.z + za.w * wa.w
                    + zb.x * wb.x + zb.y * wb.y + zb.z * wb.z + zb.w * wb.w;

            d += __shfl_xor(d, 1);
            d += __shfl_xor(d, 2);
            d += __shfl_xor(d, 4);
            d += __shfl_xor(d, 8);

            const float y  = s * d;
            const float ex = __expf(-fabsf(y));
            prod = prod * fmaf(fabsf(s), ex, 1.0f);
            accm += fminf(y, 0.0f);
        }

        acc = (accm - __logf(prod)) * 0.5f;   // 16x replicated; *1/8 in reduce
    }

    for (int off = 32; off >= 1; off >>= 1)
        acc += __shfl_down(acc, off);

    __shared__ float ws[4];
    const int wid = threadIdx.x >> 6;
    if ((threadIdx.x & 63) == 0) ws[wid] = acc;
    __syncthreads();
    if (threadIdx.x == 0)
        partials[blockIdx.x] = ws[0] + ws[1] + ws[2] + ws[3];
}

__global__ __launch_bounds__(1024) void dw_reduce(
    const float* __restrict__ partials, int n, float* __restrict__ out)
{
    float s = 0.0f;
    for (int i = threadIdx.x; i < n; i += 1024) s += partials[i];

    for (int off = 32; off >= 1; off >>= 1)
        s += __shfl_down(s, off);

    __shared__ float ws[16];
    const int wid = threadIdx.x >> 6;
    if ((threadIdx.x & 63) == 0) ws[wid] = s;
    __syncthreads();
    if (threadIdx.x == 0) {
        float b = 0.0f;
#pragma unroll
        for (int i = 0; i < 16; ++i) b += ws[i];
        out[0] = -b * 0.125f;   // undo 8x lane replication; negate per reference
    }
}

extern "C" void kernel_launch(void* const* d_in, const int* in_sizes, int n_in,
                              void* d_out, int out_size, void* d_ws, size_t ws_size,
                              hipStream_t stream)
{
    const int*   edges = (const int*)d_in[0];
    const float* Z1    = (const float*)d_in[1];
    const float* Z2    = (const float*)d_in[2];
    const int*   paths = (const int*)d_in[3];
    const float* signs = (const float*)d_in[4];
    float*       out   = (float*)d_out;

    const int E = in_sizes[0] / 2;
    const int D = in_sizes[1] - in_sizes[2];   // N*D - (N-1)*D = D
    const int N = in_sizes[1] / D;
    const int L = in_sizes[3] / N;

    const int threads  = 256;
    const int blocks32 = (E * 32 + threads - 1) / threads;
    const int blocks16 = (E * 16 + threads - 1) / threads;

    const size_t z2h_bytes = (size_t)in_sizes[2] * 2;   // fp16 copy of Z2
    const size_t part_off  = (z2h_bytes + 255) & ~(size_t)255;
    const bool   use_h     = (ws_size >= part_off + (size_t)blocks32 * 4) && (D == 128);

    if (use_h) {
        _Float16* Z2h   = (_Float16*)d_ws;
        float*    parts = (float*)((char*)d_ws + part_off);

        const int n8 = in_sizes[2] / 8;
        dw_pack_f16<<<(n8 + 255) / 256, 256, 0, stream>>>(Z2, Z2h, n8);

        if (L == 17)
            dw_kernel32<17><<<blocks32, threads, 0, stream>>>(edges, Z1, Z2h, paths, signs, parts, E, L);
        else if (L == 16)
            dw_kernel32<16><<<blocks32, threads, 0, stream>>>(edges, Z1, Z2h, paths, signs, parts, E, L);
        else if (L == 18)
            dw_kernel32<18><<<blocks32, threads, 0, stream>>>(edges, Z1, Z2h, paths, signs, parts, E, L);
        else
            dw_kernel32<0><<<blocks32, threads, 0, stream>>>(edges, Z1, Z2h, paths, signs, parts, E, L);

        dw_reduce<<<1, 1024, 0, stream>>>(parts, blocks32, out);
    } else {
        float* parts = (float*)d_ws;
        if (L == 17)
            dw_kernel_t<17><<<blocks16, threads, 0, stream>>>(edges, Z1, Z2, paths, signs, parts, E, L);
        else if (L == 16)
            dw_kernel_t<16><<<blocks16, threads, 0, stream>>>(edges, Z1, Z2, paths, signs, parts, E, L);
        else if (L == 18)
            dw_kernel_t<18><<<blocks16, threads, 0, stream>>>(edges, Z1, Z2, paths, signs, parts, E, L);
        else
            dw_kernel_t<0><<<blocks16, threads, 0, stream>>>(edges, Z1, Z2, paths, signs, parts, E, L);
        dw_reduce<<<1, 1024, 0, stream>>>(parts, blocks16, out);
    }
}

// Round 9
// 186.272 us; speedup vs baseline: 1.2267x; 1.2267x over previous
//
#include <hip/hip_runtime.h>

// DeepWalk hierarchical-softmax loss:
//   out = -sum_{e,t} mask[v,t] * log_sigmoid(signs[v,t] * dot(Z1[u], Z2[paths[v,t]]))
//
// Identities: log_sigmoid(y) = min(y,0) - log(1+exp(-|y|));
//   sum log(1+e) -> log(prod (1+e)); padded levels (s==0) contribute exactly 0.
//
// R9 = R7 (fp8 Z2, 16-lane groups, quad reduce-scatter) + manual full-depth
// gather prefetch: all L row-gathers issued into registers before any compute
// (one exposed memory latency per edge instead of one per quad), and direct
// per-lane sign load sr[t+(lane&3)] instead of 4 loads + 3 selects.

typedef float floatx2 __attribute__((ext_vector_type(2)));

__global__ __launch_bounds__(256) void dw_pack_fp8(
    const float* __restrict__ src, int* __restrict__ dst, int n8)
{
    const int i = blockIdx.x * 256 + threadIdx.x;
    if (i < n8) {
        const float4* s = (const float4*)src;
        const float4 a = s[2 * i];
        const float4 b = s[2 * i + 1];
        int r0 = __builtin_amdgcn_cvt_pk_fp8_f32(a.x, a.y, 0, false);
        r0     = __builtin_amdgcn_cvt_pk_fp8_f32(a.z, a.w, r0, true);
        int r1 = __builtin_amdgcn_cvt_pk_fp8_f32(b.x, b.y, 0, false);
        r1     = __builtin_amdgcn_cvt_pk_fp8_f32(b.z, b.w, r1, true);
        ((int2*)dst)[i] = make_int2(r0, r1);
    }
}

__device__ __forceinline__ float dw_dot8w(
    int2 w8, floatx2 z01, floatx2 z23, floatx2 z45, floatx2 z67)
{
    const floatx2 w01 = __builtin_amdgcn_cvt_pk_f32_fp8(w8.x, false);
    const floatx2 w23 = __builtin_amdgcn_cvt_pk_f32_fp8(w8.x, true);
    const floatx2 w45 = __builtin_amdgcn_cvt_pk_f32_fp8(w8.y, false);
    const floatx2 w67 = __builtin_amdgcn_cvt_pk_f32_fp8(w8.y, true);
    floatx2 d2 = w01 * z01;
    d2 = w23 * z23 + d2;
    d2 = w45 * z45 + d2;
    d2 = w67 * z67 + d2;
    return d2.x + d2.y;
}

template <int LT>
__global__ __launch_bounds__(256) void dw_kernel_q4p(
    const int* __restrict__ edges,
    const float* __restrict__ Z1,
    const int2* __restrict__ Z2q,    // fp8 e4m3, 16 int2 per row
    const int* __restrict__ paths,
    const float* __restrict__ signs,
    float* __restrict__ partials,
    int E)
{
    const int tid   = blockIdx.x * blockDim.x + threadIdx.x;
    const int group = tid >> 4;   // one edge per 16-lane subgroup
    const int lane  = tid & 15;

    float acc = 0.0f;

    if (group < E) {
        const int u = edges[2 * group];
        const int v = edges[2 * group + 1];

        // z = Z1[u] floats [8*lane..8*lane+7] (row-coalesced, 16B aligned)
        const float4* zr = (const float4*)(Z1 + (size_t)u * 128);
        const float4 za = zr[2 * lane];
        const float4 zb = zr[2 * lane + 1];
        const floatx2 z01 = {za.x, za.y};
        const floatx2 z23 = {za.z, za.w};
        const floatx2 z45 = {zb.x, zb.y};
        const floatx2 z67 = {zb.z, zb.w};

        const int*   pr = paths + (size_t)v * LT;
        const float* sr = signs + (size_t)v * LT;

        // ---- full-depth prefetch: all L gathers in flight before compute ----
        int pv[LT];
#pragma unroll
        for (int t = 0; t < LT; ++t) pv[t] = pr[t];
        int2 w[LT];
#pragma unroll
        for (int t = 0; t < LT; ++t)
            w[t] = Z2q[(unsigned)pv[t] * 16u + lane];   // 8B aligned gather

        const bool b0 = lane & 1;
        const bool b1 = lane & 2;
        const int  own = lane & 3;     // this lane owns level t + own

        float accm = 0.0f;   // sum of min(y,0)           (4x replicated)
        float prod = 1.0f;   // prod of (1 + exp(-|y|))   (4x replicated)

        int t = 0;
#pragma unroll
        for (; t + 4 <= LT; t += 4) {
            const float s = sr[t + own];   // own level's sign (0 if padded)

            const float d0 = dw_dot8w(w[t + 0], z01, z23, z45, z67);
            const float d1 = dw_dot8w(w[t + 1], z01, z23, z45, z67);
            const float d2 = dw_dot8w(w[t + 2], z01, z23, z45, z67);
            const float d3 = dw_dot8w(w[t + 3], z01, z23, z45, z67);

            // quad reduce-scatter: lane ends with full 16-lane dot of level t+own
            const float ua = b0 ? d0 : d1, ka = b0 ? d1 : d0;
            const float av = ka + __shfl_xor(ua, 1);
            const float ub = b0 ? d2 : d3, kb = b0 ? d3 : d2;
            const float bv = kb + __shfl_xor(ub, 1);
            const float uc = b1 ? av : bv, kc = b1 ? bv : av;
            float cv = kc + __shfl_xor(uc, 2);
            cv += __shfl_xor(cv, 4);
            cv += __shfl_xor(cv, 8);

            const float y  = s * cv;
            const float ex = __expf(-fabsf(y));          // 1.0 when padded
            prod = prod * fmaf(fabsf(s), ex, 1.0f);      // *1 when padded
            accm += fminf(y, 0.0f);                      // +0 when padded
        }
        // tail levels (L%4): full butterfly, counted on lanes 0..3 only
#pragma unroll
        for (; t < LT; ++t) {
            const float s = sr[t];
            float d = dw_dot8w(w[t], z01, z23, z45, z67);
            d += __shfl_xor(d, 1);
            d += __shfl_xor(d, 2);
            d += __shfl_xor(d, 4);
            d += __shfl_xor(d, 8);
            const float y  = s * d;
            const float ex = __expf(-fabsf(y));
            const float m  = (lane < 4) ? 1.0f : 0.0f;
            prod = prod * fmaf(m * fabsf(s), ex, 1.0f);
            accm += m * fminf(y, 0.0f);
        }

        acc = accm - __logf(prod);   // per-edge contribution (4x replicated)
    }

    for (int off = 32; off >= 1; off >>= 1)
        acc += __shfl_down(acc, off);

    __shared__ float ws[4];
    const int wid = threadIdx.x >> 6;
    if ((threadIdx.x & 63) == 0) ws[wid] = acc;
    __syncthreads();
    if (threadIdx.x == 0)
        partials[blockIdx.x] = ws[0] + ws[1] + ws[2] + ws[3];
}

// runtime-L variant (no prefetch arrays) — R7's proven loop
__global__ __launch_bounds__(256) void dw_kernel_q4d(
    const int* __restrict__ edges,
    const float* __restrict__ Z1,
    const int2* __restrict__ Z2q,
    const int* __restrict__ paths,
    const float* __restrict__ signs,
    float* __restrict__ partials,
    int E, int L)
{
    const int tid   = blockIdx.x * blockDim.x + threadIdx.x;
    const int group = tid >> 4;
    const int lane  = tid & 15;

    float acc = 0.0f;

    if (group < E) {
        const int u = edges[2 * group];
        const int v = edges[2 * group + 1];

        const float4* zr = (const float4*)(Z1 + (size_t)u * 128);
        const float4 za = zr[2 * lane];
        const float4 zb = zr[2 * lane + 1];
        const floatx2 z01 = {za.x, za.y};
        const floatx2 z23 = {za.z, za.w};
        const floatx2 z45 = {zb.x, zb.y};
        const floatx2 z67 = {zb.z, zb.w};

        const int*   pr = paths + (size_t)v * L;
        const float* sr = signs + (size_t)v * L;

        const bool b0 = lane & 1;
        const bool b1 = lane & 2;
        const int  own = lane & 3;

        float accm = 0.0f;
        float prod = 1.0f;

        int t = 0;
        for (; t + 4 <= L; t += 4) {
            const float s = sr[t + own];
            const float d0 = dw_dot8w(Z2q[(unsigned)pr[t + 0] * 16u + lane], z01, z23, z45, z67);
            const float d1 = dw_dot8w(Z2q[(unsigned)pr[t + 1] * 16u + lane], z01, z23, z45, z67);
            const float d2 = dw_dot8w(Z2q[(unsigned)pr[t + 2] * 16u + lane], z01, z23, z45, z67);
            const float d3 = dw_dot8w(Z2q[(unsigned)pr[t + 3] * 16u + lane], z01, z23, z45, z67);

            const float ua = b0 ? d0 : d1, ka = b0 ? d1 : d0;
            const float av = ka + __shfl_xor(ua, 1);
            const float ub = b0 ? d2 : d3, kb = b0 ? d3 : d2;
            const float bv = kb + __shfl_xor(ub, 1);
            const float uc = b1 ? av : bv, kc = b1 ? bv : av;
            float cv = kc + __shfl_xor(uc, 2);
            cv += __shfl_xor(cv, 4);
            cv += __shfl_xor(cv, 8);

            const float s2 = s;
            const float y  = s2 * cv;
            const float ex = __expf(-fabsf(y));
            prod = prod * fmaf(fabsf(s2), ex, 1.0f);
            accm += fminf(y, 0.0f);
        }
        for (; t < L; ++t) {
            const float s = sr[t];
            float d = dw_dot8w(Z2q[(unsigned)pr[t] * 16u + lane], z01, z23, z45, z67);
            d += __shfl_xor(d, 1);
            d += __shfl_xor(d, 2);
            d += __shfl_xor(d, 4);
            d += __shfl_xor(d, 8);
            const float y  = s * d;
            const float ex = __expf(-fabsf(y));
            const float m  = (lane < 4) ? 1.0f : 0.0f;
            prod = prod * fmaf(m * fabsf(s), ex, 1.0f);
            accm += m * fminf(y, 0.0f);
        }

        acc = accm - __logf(prod);
    }

    for (int off = 32; off >= 1; off >>= 1)
        acc += __shfl_down(acc, off);

    __shared__ float ws[4];
    const int wid = threadIdx.x >> 6;
    if ((threadIdx.x & 63) == 0) ws[wid] = acc;
    __syncthreads();
    if (threadIdx.x == 0)
        partials[blockIdx.x] = ws[0] + ws[1] + ws[2] + ws[3];
}

// fp32 fallback if ws too small (16x replication -> *0.25 here, *0.25 in reduce)
template <int LT>
__global__ __launch_bounds__(256) void dw_kernel_t(
    const int* __restrict__ edges,
    const float* __restrict__ Z1,
    const float* __restrict__ Z2,
    const int* __restrict__ paths,
    const float* __restrict__ signs,
    float* __restrict__ partials,
    int E, int L_rt)
{
    const int tid   = blockIdx.x * blockDim.x + threadIdx.x;
    const int group = tid >> 4;
    const int lane  = tid & 15;
    const int L     = (LT > 0) ? LT : L_rt;

    float acc = 0.0f;

    if (group < E) {
        const int u = edges[2 * group];
        const int v = edges[2 * group + 1];

        const float4* zr = (const float4*)(Z1 + (size_t)u * 128);
        const float4 za = zr[lane];
        const float4 zb = zr[lane + 16];

        const int*    pr  = paths + (size_t)v * L;
        const float*  sr  = signs + (size_t)v * L;
        const float4* Z2v = (const float4*)Z2;

        float accm = 0.0f;
        float prod = 1.0f;

#pragma unroll
        for (int t = 0; t < L; ++t) {
            const int   p = pr[t];
            const float s = sr[t];

            const float4 wa = Z2v[p * 32 + lane];
            const float4 wb = Z2v[p * 32 + lane + 16];

            float d = za.x * wa.x + za.y * wa.y + za.z * wa.z + za.w * wa.w
                    + zb.x * wb.x + zb.y * wb.y + zb.z * wb.z + zb.w * wb.w;

            d += __shfl_xor(d, 1);
            d += __shfl_xor(d, 2);
            d += __shfl_xor(d, 4);
            d += __shfl_xor(d, 8);

            const float y  = s * d;
            const float ex = __expf(-fabsf(y));
            prod = prod * fmaf(fabsf(s), ex, 1.0f);
            accm += fminf(y, 0.0f);
        }

        acc = (accm - __logf(prod)) * 0.25f;
    }

    for (int off = 32; off >= 1; off >>= 1)
        acc += __shfl_down(acc, off);

    __shared__ float ws[4];
    const int wid = threadIdx.x >> 6;
    if ((threadIdx.x & 63) == 0) ws[wid] = acc;
    __syncthreads();
    if (threadIdx.x == 0)
        partials[blockIdx.x] = ws[0] + ws[1] + ws[2] + ws[3];
}

__global__ __launch_bounds__(1024) void dw_reduce(
    const float* __restrict__ partials, int n, float* __restrict__ out)
{
    float s = 0.0f;
    for (int i = threadIdx.x; i < n; i += 1024) s += partials[i];

    for (int off = 32; off >= 1; off >>= 1)
        s += __shfl_down(s, off);

    __shared__ float ws[16];
    const int wid = threadIdx.x >> 6;
    if ((threadIdx.x & 63) == 0) ws[wid] = s;
    __syncthreads();
    if (threadIdx.x == 0) {
        float b = 0.0f;
#pragma unroll
        for (int i = 0; i < 16; ++i) b += ws[i];
        out[0] = -b * 0.25f;   // undo 4x lane replication; negate per reference
    }
}

extern "C" void kernel_launch(void* const* d_in, const int* in_sizes, int n_in,
                              void* d_out, int out_size, void* d_ws, size_t ws_size,
                              hipStream_t stream)
{
    const int*   edges = (const int*)d_in[0];
    const float* Z1    = (const float*)d_in[1];
    const float* Z2    = (const float*)d_in[2];
    const int*   paths = (const int*)d_in[3];
    const float* signs = (const float*)d_in[4];
    float*       out   = (float*)d_out;

    const int E = in_sizes[0] / 2;
    const int D = in_sizes[1] - in_sizes[2];   // N*D - (N-1)*D = D
    const int N = in_sizes[1] / D;
    const int L = in_sizes[3] / N;

    const int threads = 256;
    const int blocks  = (E * 16 + threads - 1) / threads;

    const size_t z2q_bytes = (size_t)in_sizes[2];   // 1 byte per element
    const size_t part_off  = (z2q_bytes + 255) & ~(size_t)255;
    const bool   use_q     = (ws_size >= part_off + (size_t)blocks * 4) && (D == 128);

    if (use_q) {
        int2*  Z2q   = (int2*)d_ws;
        float* parts = (float*)((char*)d_ws + part_off);

        const int n8 = in_sizes[2] / 8;
        dw_pack_fp8<<<(n8 + 255) / 256, 256, 0, stream>>>(Z2, (int*)Z2q, n8);

        if (L == 17)
            dw_kernel_q4p<17><<<blocks, threads, 0, stream>>>(edges, Z1, Z2q, paths, signs, parts, E);
        else if (L == 16)
            dw_kernel_q4p<16><<<blocks, threads, 0, stream>>>(edges, Z1, Z2q, paths, signs, parts, E);
        else if (L == 18)
            dw_kernel_q4p<18><<<blocks, threads, 0, stream>>>(edges, Z1, Z2q, paths, signs, parts, E);
        else
            dw_kernel_q4d<<<blocks, threads, 0, stream>>>(edges, Z1, Z2q, paths, signs, parts, E, L);

        dw_reduce<<<1, 1024, 0, stream>>>(parts, blocks, out);
    } else {
        float* parts = (float*)d_ws;
        if (L == 17)
            dw_kernel_t<17><<<blocks, threads, 0, stream>>>(edges, Z1, Z2, paths, signs, parts, E, L);
        else if (L == 16)
            dw_kernel_t<16><<<blocks, threads, 0, stream>>>(edges, Z1, Z2, paths, signs, parts, E, L);
        else if (L == 18)
            dw_kernel_t<18><<<blocks, threads, 0, stream>>>(edges, Z1, Z2, paths, signs, parts, E, L);
        else
            dw_kernel_t<0><<<blocks, threads, 0, stream>>>(edges, Z1, Z2, paths, signs, parts, E, L);
        dw_reduce<<<1, 1024, 0, stream>>>(parts, blocks, out);
    }
}

// Round 10
// 185.445 us; speedup vs baseline: 1.2322x; 1.0045x over previous
//
#include <hip/hip_runtime.h>

// DeepWalk hierarchical-softmax loss:
//   out = -sum_{e,t} mask[v,t] * log_sigmoid(signs[v,t] * dot(Z1[u], Z2[paths[v,t]]))
//
// Identities: log_sigmoid(y) = min(y,0) - log(1+exp(-|y|));
//   sum log(1+e) -> log(prod (1+e)); padded levels (s==0) contribute exactly 0.
//
// R10 = R9 (fp8 Z2, 16-lane groups, quad reduce-scatter) + sched_barrier(0)-
// FORCED two-phase prefetch: all 17 path-ids loaded (phase 1), then all 17
// row-gathers issued (phase 2), then compute. Two exposed latency periods per
// wave instead of ~4-5 chained p->row pairs. Signs prefetched upfront too.

typedef float floatx2 __attribute__((ext_vector_type(2)));

#if defined(__has_builtin)
#if __has_builtin(__builtin_amdgcn_sched_barrier)
#define SCHED_FENCE() __builtin_amdgcn_sched_barrier(0)
#endif
#endif
#ifndef SCHED_FENCE
#define SCHED_FENCE() do {} while (0)
#endif

__global__ __launch_bounds__(256) void dw_pack_fp8(
    const float* __restrict__ src, int* __restrict__ dst, int n8)
{
    const int i = blockIdx.x * 256 + threadIdx.x;
    if (i < n8) {
        const float4* s = (const float4*)src;
        const float4 a = s[2 * i];
        const float4 b = s[2 * i + 1];
        int r0 = __builtin_amdgcn_cvt_pk_fp8_f32(a.x, a.y, 0, false);
        r0     = __builtin_amdgcn_cvt_pk_fp8_f32(a.z, a.w, r0, true);
        int r1 = __builtin_amdgcn_cvt_pk_fp8_f32(b.x, b.y, 0, false);
        r1     = __builtin_amdgcn_cvt_pk_fp8_f32(b.z, b.w, r1, true);
        ((int2*)dst)[i] = make_int2(r0, r1);
    }
}

__device__ __forceinline__ float dw_dot8w(
    int2 w8, floatx2 z01, floatx2 z23, floatx2 z45, floatx2 z67)
{
    const floatx2 w01 = __builtin_amdgcn_cvt_pk_f32_fp8(w8.x, false);
    const floatx2 w23 = __builtin_amdgcn_cvt_pk_f32_fp8(w8.x, true);
    const floatx2 w45 = __builtin_amdgcn_cvt_pk_f32_fp8(w8.y, false);
    const floatx2 w67 = __builtin_amdgcn_cvt_pk_f32_fp8(w8.y, true);
    floatx2 d2 = w01 * z01;
    d2 = w23 * z23 + d2;
    d2 = w45 * z45 + d2;
    d2 = w67 * z67 + d2;
    return d2.x + d2.y;
}

template <int LT>
__global__ __launch_bounds__(256) void dw_kernel_q4p(
    const int* __restrict__ edges,
    const float* __restrict__ Z1,
    const int2* __restrict__ Z2q,    // fp8 e4m3, 16 int2 per row
    const int* __restrict__ paths,
    const float* __restrict__ signs,
    float* __restrict__ partials,
    int E)
{
    const int tid   = blockIdx.x * blockDim.x + threadIdx.x;
    const int group = tid >> 4;   // one edge per 16-lane subgroup
    const int lane  = tid & 15;
    constexpr int NQ = LT / 4;    // full quads
    constexpr int NT = LT - 4 * NQ;

    float acc = 0.0f;

    if (group < E) {
        const int2 uv = ((const int2*)edges)[group];
        const int u = uv.x;
        const int v = uv.y;

        const int*   pr = paths + (size_t)v * LT;
        const float* sr = signs + (size_t)v * LT;

        const int own = lane & 3;      // this lane owns level 4q + own

        // ---- phase 0: z row + path ids + owned signs, all independent ----
        const float4* zr = (const float4*)(Z1 + (size_t)u * 128);
        const float4 za = zr[2 * lane];
        const float4 zb = zr[2 * lane + 1];

        int pv[LT];
#pragma unroll
        for (int t = 0; t < LT; ++t) pv[t] = pr[t];

        float sv[NQ];
#pragma unroll
        for (int q = 0; q < NQ; ++q) sv[q] = sr[4 * q + own];
        float st[NT > 0 ? NT : 1];
#pragma unroll
        for (int j = 0; j < NT; ++j) st[j] = sr[4 * NQ + j];

        SCHED_FENCE();

        // ---- phase 1: ALL row-gathers issued before any compute ----
        int2 w[LT];
#pragma unroll
        for (int t = 0; t < LT; ++t)
            w[t] = Z2q[(unsigned)pv[t] * 16u + lane];   // 8B aligned gather

        SCHED_FENCE();

        // ---- phase 2: compute ----
        const floatx2 z01 = {za.x, za.y};
        const floatx2 z23 = {za.z, za.w};
        const floatx2 z45 = {zb.x, zb.y};
        const floatx2 z67 = {zb.z, zb.w};

        const bool b0 = lane & 1;
        const bool b1 = lane & 2;

        float accm = 0.0f;   // sum of min(y,0)           (4x replicated)
        float prod = 1.0f;   // prod of (1 + exp(-|y|))   (4x replicated)

#pragma unroll
        for (int q = 0; q < NQ; ++q) {
            const int t = 4 * q;
            const float s = sv[q];   // own level's sign (0 if padded)

            const float d0 = dw_dot8w(w[t + 0], z01, z23, z45, z67);
            const float d1 = dw_dot8w(w[t + 1], z01, z23, z45, z67);
            const float d2 = dw_dot8w(w[t + 2], z01, z23, z45, z67);
            const float d3 = dw_dot8w(w[t + 3], z01, z23, z45, z67);

            // quad reduce-scatter: lane ends with full 16-lane dot of level t+own
            const float ua = b0 ? d0 : d1, ka = b0 ? d1 : d0;
            const float av = ka + __shfl_xor(ua, 1);
            const float ub = b0 ? d2 : d3, kb = b0 ? d3 : d2;
            const float bv = kb + __shfl_xor(ub, 1);
            const float uc = b1 ? av : bv, kc = b1 ? bv : av;
            float cv = kc + __shfl_xor(uc, 2);
            cv += __shfl_xor(cv, 4);
            cv += __shfl_xor(cv, 8);

            const float y  = s * cv;
            const float ex = __expf(-fabsf(y));          // 1.0 when padded
            prod = prod * fmaf(fabsf(s), ex, 1.0f);      // *1 when padded
            accm += fminf(y, 0.0f);                      // +0 when padded
        }
        // tail levels (L%4): full butterfly, counted on lanes 0..3 only
#pragma unroll
        for (int j = 0; j < NT; ++j) {
            const int t = 4 * NQ + j;
            const float s = st[j];
            float d = dw_dot8w(w[t], z01, z23, z45, z67);
            d += __shfl_xor(d, 1);
            d += __shfl_xor(d, 2);
            d += __shfl_xor(d, 4);
            d += __shfl_xor(d, 8);
            const float y  = s * d;
            const float ex = __expf(-fabsf(y));
            const float m  = (lane < 4) ? 1.0f : 0.0f;
            prod = prod * fmaf(m * fabsf(s), ex, 1.0f);
            accm += m * fminf(y, 0.0f);
        }

        acc = accm - __logf(prod);   // per-edge contribution (4x replicated)
    }

    for (int off = 32; off >= 1; off >>= 1)
        acc += __shfl_down(acc, off);

    __shared__ float ws[4];
    const int wid = threadIdx.x >> 6;
    if ((threadIdx.x & 63) == 0) ws[wid] = acc;
    __syncthreads();
    if (threadIdx.x == 0)
        partials[blockIdx.x] = ws[0] + ws[1] + ws[2] + ws[3];
}

// runtime-L variant — R7's proven loop
__global__ __launch_bounds__(256) void dw_kernel_q4d(
    const int* __restrict__ edges,
    const float* __restrict__ Z1,
    const int2* __restrict__ Z2q,
    const int* __restrict__ paths,
    const float* __restrict__ signs,
    float* __restrict__ partials,
    int E, int L)
{
    const int tid   = blockIdx.x * blockDim.x + threadIdx.x;
    const int group = tid >> 4;
    const int lane  = tid & 15;

    float acc = 0.0f;

    if (group < E) {
        const int u = edges[2 * group];
        const int v = edges[2 * group + 1];

        const float4* zr = (const float4*)(Z1 + (size_t)u * 128);
        const float4 za = zr[2 * lane];
        const float4 zb = zr[2 * lane + 1];
        const floatx2 z01 = {za.x, za.y};
        const floatx2 z23 = {za.z, za.w};
        const floatx2 z45 = {zb.x, zb.y};
        const floatx2 z67 = {zb.z, zb.w};

        const int*   pr = paths + (size_t)v * L;
        const float* sr = signs + (size_t)v * L;

        const bool b0 = lane & 1;
        const bool b1 = lane & 2;
        const int  own = lane & 3;

        float accm = 0.0f;
        float prod = 1.0f;

        int t = 0;
        for (; t + 4 <= L; t += 4) {
            const float s = sr[t + own];
            const float d0 = dw_dot8w(Z2q[(unsigned)pr[t + 0] * 16u + lane], z01, z23, z45, z67);
            const float d1 = dw_dot8w(Z2q[(unsigned)pr[t + 1] * 16u + lane], z01, z23, z45, z67);
            const float d2 = dw_dot8w(Z2q[(unsigned)pr[t + 2] * 16u + lane], z01, z23, z45, z67);
            const float d3 = dw_dot8w(Z2q[(unsigned)pr[t + 3] * 16u + lane], z01, z23, z45, z67);

            const float ua = b0 ? d0 : d1, ka = b0 ? d1 : d0;
            const float av = ka + __shfl_xor(ua, 1);
            const float ub = b0 ? d2 : d3, kb = b0 ? d3 : d2;
            const float bv = kb + __shfl_xor(ub, 1);
            const float uc = b1 ? av : bv, kc = b1 ? bv : av;
            float cv = kc + __shfl_xor(uc, 2);
            cv += __shfl_xor(cv, 4);
            cv += __shfl_xor(cv, 8);

            const float y  = s * cv;
            const float ex = __expf(-fabsf(y));
            prod = prod * fmaf(fabsf(s), ex, 1.0f);
            accm += fminf(y, 0.0f);
        }
        for (; t < L; ++t) {
            const float s = sr[t];
            float d = dw_dot8w(Z2q[(unsigned)pr[t] * 16u + lane], z01, z23, z45, z67);
            d += __shfl_xor(d, 1);
            d += __shfl_xor(d, 2);
            d += __shfl_xor(d, 4);
            d += __shfl_xor(d, 8);
            const float y  = s * d;
            const float ex = __expf(-fabsf(y));
            const float m  = (lane < 4) ? 1.0f : 0.0f;
            prod = prod * fmaf(m * fabsf(s), ex, 1.0f);
            accm += m * fminf(y, 0.0f);
        }

        acc = accm - __logf(prod);
    }

    for (int off = 32; off >= 1; off >>= 1)
        acc += __shfl_down(acc, off);

    __shared__ float ws[4];
    const int wid = threadIdx.x >> 6;
    if ((threadIdx.x & 63) == 0) ws[wid] = acc;
    __syncthreads();
    if (threadIdx.x == 0)
        partials[blockIdx.x] = ws[0] + ws[1] + ws[2] + ws[3];
}

// fp32 fallback if ws too small
template <int LT>
__global__ __launch_bounds__(256) void dw_kernel_t(
    const int* __restrict__ edges,
    const float* __restrict__ Z1,
    const float* __restrict__ Z2,
    const int* __restrict__ paths,
    const float* __restrict__ signs,
    float* __restrict__ partials,
    int E, int L_rt)
{
    const int tid   = blockIdx.x * blockDim.x + threadIdx.x;
    const int group = tid >> 4;
    const int lane  = tid & 15;
    const int L     = (LT > 0) ? LT : L_rt;

    float acc = 0.0f;

    if (group < E) {
        const int u = edges[2 * group];
        const int v = edges[2 * group + 1];

        const float4* zr = (const float4*)(Z1 + (size_t)u * 128);
        const float4 za = zr[lane];
        const float4 zb = zr[lane + 16];

        const int*    pr  = paths + (size_t)v * L;
        const float*  sr  = signs + (size_t)v * L;
        const float4* Z2v = (const float4*)Z2;

        float accm = 0.0f;
        float prod = 1.0f;

#pragma unroll
        for (int t = 0; t < L; ++t) {
            const int   p = pr[t];
            const float s = sr[t];

            const float4 wa = Z2v[p * 32 + lane];
            const float4 wb = Z2v[p * 32 + lane + 16];

            float d = za.x * wa.x + za.y * wa.y + za.z * wa.z + za.w * wa.w
                    + zb.x * wb.x + zb.y * wb.y + zb.z * wb.z + zb.w * wb.w;

            d += __shfl_xor(d, 1);
            d += __shfl_xor(d, 2);
            d += __shfl_xor(d, 4);
            d += __shfl_xor(d, 8);

            const float y  = s * d;
            const float ex = __expf(-fabsf(y));
            prod = prod * fmaf(fabsf(s), ex, 1.0f);
            accm += fminf(y, 0.0f);
        }

        acc = (accm - __logf(prod)) * 0.25f;
    }

    for (int off = 32; off >= 1; off >>= 1)
        acc += __shfl_down(acc, off);

    __shared__ float ws[4];
    const int wid = threadIdx.x >> 6;
    if ((threadIdx.x & 63) == 0) ws[wid] = acc;
    __syncthreads();
    if (threadIdx.x == 0)
        partials[blockIdx.x] = ws[0] + ws[1] + ws[2] + ws[3];
}

__global__ __launch_bounds__(1024) void dw_reduce(
    const float* __restrict__ partials, int n, float* __restrict__ out)
{
    float s = 0.0f;
    for (int i = threadIdx.x; i < n; i += 1024) s += partials[i];

    for (int off = 32; off >= 1; off >>= 1)
        s += __shfl_down(s, off);

    __shared__ float ws[16];
    const int wid = threadIdx.x >> 6;
    if ((threadIdx.x & 63) == 0) ws[wid] = s;
    __syncthreads();
    if (threadIdx.x == 0) {
        float b = 0.0f;
#pragma unroll
        for (int i = 0; i < 16; ++i) b += ws[i];
        out[0] = -b * 0.25f;   // undo 4x lane replication; negate per reference
    }
}

extern "C" void kernel_launch(void* const* d_in, const int* in_sizes, int n_in,
                              void* d_out, int out_size, void* d_ws, size_t ws_size,
                              hipStream_t stream)
{
    const int*   edges = (const int*)d_in[0];
    const float* Z1    = (const float*)d_in[1];
    const float* Z2    = (const float*)d_in[2];
    const int*   paths = (const int*)d_in[3];
    const float* signs = (const float*)d_in[4];
    float*       out   = (float*)d_out;

    const int E = in_sizes[0] / 2;
    const int D = in_sizes[1] - in_sizes[2];   // N*D - (N-1)*D = D
    const int N = in_sizes[1] / D;
    const int L = in_sizes[3] / N;

    const int threads = 256;
    const int blocks  = (E * 16 + threads - 1) / threads;

    const size_t z2q_bytes = (size_t)in_sizes[2];   // 1 byte per element
    const size_t part_off  = (z2q_bytes + 255) & ~(size_t)255;
    const bool   use_q     = (ws_size >= part_off + (size_t)blocks * 4) && (D == 128);

    if (use_q) {
        int2*  Z2q   = (int2*)d_ws;
        float* parts = (float*)((char*)d_ws + part_off);

        const int n8 = in_sizes[2] / 8;
        dw_pack_fp8<<<(n8 + 255) / 256, 256, 0, stream>>>(Z2, (int*)Z2q, n8);

        if (L == 17)
            dw_kernel_q4p<17><<<blocks, threads, 0, stream>>>(edges, Z1, Z2q, paths, signs, parts, E);
        else if (L == 16)
            dw_kernel_q4p<16><<<blocks, threads, 0, stream>>>(edges, Z1, Z2q, paths, signs, parts, E);
        else if (L == 18)
            dw_kernel_q4p<18><<<blocks, threads, 0, stream>>>(edges, Z1, Z2q, paths, signs, parts, E);
        else
            dw_kernel_q4d<<<blocks, threads, 0, stream>>>(edges, Z1, Z2q, paths, signs, parts, E, L);

        dw_reduce<<<1, 1024, 0, stream>>>(parts, blocks, out);
    } else {
        float* parts = (float*)d_ws;
        if (L == 17)
            dw_kernel_t<17><<<blocks, threads, 0, stream>>>(edges, Z1, Z2, paths, signs, parts, E, L);
        else if (L == 16)
            dw_kernel_t<16><<<blocks, threads, 0, stream>>>(edges, Z1, Z2, paths, signs, parts, E, L);
        else if (L == 18)
            dw_kernel_t<18><<<blocks, threads, 0, stream>>>(edges, Z1, Z2, paths, signs, parts, E, L);
        else
            dw_kernel_t<0><<<blocks, threads, 0, stream>>>(edges, Z1, Z2, paths, signs, parts, E, L);
        dw_reduce<<<1, 1024, 0, stream>>>(parts, blocks, out);
    }
}